// Round 7
// baseline (21.601 us; speedup 1.0000x reference)
//
#include <hip/hip_runtime.h>

#define MARGIN 0.1f
#define NBEST 64
#define RPW 8          // rows per wave
#define GRP 8          // blocks per level-1 counter group

// ws layout (floats): [0..4095] block partials; counters at 16K offset.
#define CNT1_OFF (16384 / 4)         // u32 index base for level-1 counters
#define CNT1_STRIDE 16               // 64B apart
#define CNT2_OFF (CNT1_OFF + 64 * CNT1_STRIDE + CNT1_STRIDE)

// One wave processes 8 rows. LDS holds Q = g + margin; inner loop uses
// max(Q_c, g_i) and the identity max(x-b,0) = max(x,b)-b, so each pair is
// just v_max + v_fma (mask multiplier). The -g_i*count term is one epilogue
// fma per row. Last block (hierarchical mod-counters, no reset needed)
// reduces all partials and writes out.
__global__ __launch_bounds__(256)
void sml_kernel(const float* __restrict__ scores,
                const unsigned int* __restrict__ wr32,
                float* __restrict__ ws, float* __restrict__ out,
                int B, int lastblock)
{
    const int lane = threadIdx.x & 63;
    const int wib  = threadIdx.x >> 6;                 // wave-in-block 0..3
    const int b0   = (blockIdx.x * 4 + wib) * RPW;     // first row of wave

    // werRank width probe (int64 vs int32), wave-uniform: int64 values in
    // [0,64) -> every odd int32 word is 0.
    unsigned int probe = wr32[2 * lane + 1];
    const bool is64 = (__all(probe == 0u) != 0);

    // Gather: lane owns column i=lane of each of its 8 rows.
    unsigned int rk[RPW];
    #pragma unroll
    for (int r = 0; r < RPW; ++r) {
        int bc  = min(b0 + r, B - 1);
        rk[r] = is64 ? wr32[2 * (bc * NBEST + lane)] : wr32[bc * NBEST + lane];
    }
    float gv[RPW];
    #pragma unroll
    for (int r = 0; r < RPW; ++r) {
        int bc = min(b0 + r, B - 1);
        gv[r] = scores[bc * NBEST + (int)(rk[r] & (NBEST - 1))];
    }

    __shared__ float4 q4[4][2][NBEST];   // [wave][row-half][column], Q = g+M
    q4[wib][0][lane] = make_float4(gv[0] + MARGIN, gv[1] + MARGIN,
                                   gv[2] + MARGIN, gv[3] + MARGIN);
    q4[wib][1][lane] = make_float4(gv[4] + MARGIN, gv[5] + MARGIN,
                                   gv[6] + MARGIN, gv[7] + MARGIN);

    float acc[RPW];
    #pragma unroll
    for (int r = 0; r < RPW; ++r) acc[r] = 0.0f;

    __syncthreads();

    // acc[r] += max(Q_r[c], g_r[lane]) * (lane < c)
    #pragma unroll
    for (int c = 1; c < NBEST; ++c) {
        float4 qa = q4[wib][0][c];
        float4 qb = q4[wib][1][c];
        float mm = (lane < c) ? 1.0f : 0.0f;           // shared by 8 rows
        acc[0] = fmaf(fmaxf(qa.x, gv[0]), mm, acc[0]);
        acc[1] = fmaf(fmaxf(qa.y, gv[1]), mm, acc[1]);
        acc[2] = fmaf(fmaxf(qa.z, gv[2]), mm, acc[2]);
        acc[3] = fmaf(fmaxf(qa.w, gv[3]), mm, acc[3]);
        acc[4] = fmaf(fmaxf(qb.x, gv[4]), mm, acc[4]);
        acc[5] = fmaf(fmaxf(qb.y, gv[5]), mm, acc[5]);
        acc[6] = fmaf(fmaxf(qb.z, gv[6]), mm, acc[6]);
        acc[7] = fmaf(fmaxf(qb.w, gv[7]), mm, acc[7]);
    }

    // Subtract g_i * (#masked terms) and apply mean denominator.
    const float cntf = (float)((NBEST - 1) - lane);
    float accs = 0.0f;
    #pragma unroll
    for (int r = 0; r < RPW; ++r) {
        float ar = fmaf(-gv[r], cntf, acc[r]);
        accs += (b0 + r < B) ? ar : 0.0f;
    }
    int cnt = (NBEST - 1) - lane;                      // lane 63: acc==0
    float accv = accs / (float)(cnt > 0 ? cnt : 1);

    #pragma unroll
    for (int off = 32; off > 0; off >>= 1)
        accv += __shfl_down(accv, off);

    __shared__ float wsum[4];
    if (lane == 0) wsum[wib] = accv;
    __syncthreads();

    if (!lastblock) {
        if (threadIdx.x == 0)
            ws[blockIdx.x] = wsum[0] + wsum[1] + wsum[2] + wsum[3];
        return;
    }

    // ---- single-kernel finish: hierarchical mod-counter last-block ----
    __shared__ int amlast;
    if (threadIdx.x == 0) {
        ws[blockIdx.x] = wsum[0] + wsum[1] + wsum[2] + wsum[3];
        __threadfence();                               // release partial
        unsigned int* cnt1 = (unsigned int*)ws + CNT1_OFF;
        unsigned int* cnt2 = (unsigned int*)ws + CNT2_OFF;
        unsigned g = (unsigned)blockIdx.x / GRP;
        unsigned o1 = atomicAdd(&cnt1[g * CNT1_STRIDE], 1u);
        int last = 0;
        if (((o1 + 1u) & (GRP - 1u)) == 0u) {          // last in group of 8
            __threadfence();                           // acquire group stores
            unsigned o2 = atomicAdd(cnt2, 1u);
            unsigned ngroups = gridDim.x / GRP;
            last = (((o2 + 1u) & (ngroups - 1u)) == 0u);
        }
        amlast = last;
    }
    __syncthreads();
    if (amlast) {
        __threadfence();                               // acquire all partials
        const int n = gridDim.x;
        float s = 0.0f;
        for (int i = threadIdx.x; i < n; i += 256) s += ws[i];
        #pragma unroll
        for (int off = 32; off > 0; off >>= 1)
            s += __shfl_down(s, off);
        __shared__ float w2[4];
        if (lane == 0) w2[wib] = s;
        __syncthreads();
        if (threadIdx.x == 0)
            out[0] = w2[0] + w2[1] + w2[2] + w2[3];
    }
}

// Fallback finisher (non-pow2 grids only).
__global__ __launch_bounds__(256)
void sml_reduce(const float* __restrict__ ws, float* __restrict__ out, int n)
{
    const int lane = threadIdx.x & 63;
    const int wid  = threadIdx.x >> 6;
    float s = 0.0f;
    for (int i = threadIdx.x; i < n; i += 256) s += ws[i];
    #pragma unroll
    for (int off = 32; off > 0; off >>= 1)
        s += __shfl_down(s, off);
    __shared__ float wsum[4];
    if (lane == 0) wsum[wid] = s;
    __syncthreads();
    if (threadIdx.x == 0)
        out[0] = wsum[0] + wsum[1] + wsum[2] + wsum[3];
}

extern "C" void kernel_launch(void* const* d_in, const int* in_sizes, int n_in,
                              void* d_out, int out_size, void* d_ws, size_t ws_size,
                              hipStream_t stream)
{
    const float* scores    = (const float*)d_in[0];
    const unsigned int* wr = (const unsigned int*)d_in[1];
    const int B = in_sizes[0] / NBEST;

    const int rows_per_block = 4 * RPW;                           // 32
    const int blocks = (B + rows_per_block - 1) / rows_per_block; // 512
    const int ngroups = blocks / GRP;
    // Mod-counter trick needs: blocks % GRP == 0 and ngroups a power of 2
    // (so per-call increments divide 2^32 and wraparound stays consistent).
    const bool single = (blocks % GRP == 0) && ((ngroups & (ngroups - 1)) == 0);

    sml_kernel<<<blocks, 256, 0, stream>>>(scores, wr, (float*)d_ws,
                                           (float*)d_out, B, single ? 1 : 0);
    if (!single)
        sml_reduce<<<1, 256, 0, stream>>>((const float*)d_ws, (float*)d_out,
                                          blocks);
}

// Round 9
// 15.246 us; speedup vs baseline: 1.4168x; 1.4168x over previous
//
#include <hip/hip_runtime.h>

#define MARGIN 0.1f
#define NBEST 64
#define RPW 8          // rows per wave

// One wave processes 8 rows. LDS holds Q = g + margin as two float4s per
// column; each column costs 2 broadcast ds_read_b128 (same addr across all
// lanes -> conflict-free; LDS pipe overlaps VALU). Inner pair cost is
// v_max + v_fma via the identity max(x-b,0) = max(x,b) - b; the -g_i*count
// term folds into one epilogue fma per row. Partials -> ws (plain stores),
// a separate 1-block kernel reduces. No atomics, no counters.
__global__ __launch_bounds__(256)
void sml_kernel(const float* __restrict__ scores,
                const unsigned int* __restrict__ wr32,
                float* __restrict__ ws, int B)
{
    const int lane = threadIdx.x & 63;
    const int wib  = threadIdx.x >> 6;                 // wave-in-block 0..3
    const int b0   = (blockIdx.x * 4 + wib) * RPW;     // first row of wave

    // werRank width probe (int64 vs int32), wave-uniform: int64 values in
    // [0,64) -> every odd int32 word is 0.
    unsigned int probe = wr32[2 * lane + 1];
    const bool is64 = (__all(probe == 0u) != 0);

    // Gather: lane owns column i=lane of each of its 8 rows.
    unsigned int rk[RPW];
    #pragma unroll
    for (int r = 0; r < RPW; ++r) {
        int bc = min(b0 + r, B - 1);
        rk[r] = is64 ? wr32[2 * (bc * NBEST + lane)] : wr32[bc * NBEST + lane];
    }
    float gv[RPW];
    #pragma unroll
    for (int r = 0; r < RPW; ++r) {
        int bc = min(b0 + r, B - 1);
        gv[r] = scores[bc * NBEST + (int)(rk[r] & (NBEST - 1))];
    }

    __shared__ float4 q4[4][2][NBEST];   // [wave][row-half][column], Q = g+M
    q4[wib][0][lane] = make_float4(gv[0] + MARGIN, gv[1] + MARGIN,
                                   gv[2] + MARGIN, gv[3] + MARGIN);
    q4[wib][1][lane] = make_float4(gv[4] + MARGIN, gv[5] + MARGIN,
                                   gv[6] + MARGIN, gv[7] + MARGIN);

    float acc[RPW];
    #pragma unroll
    for (int r = 0; r < RPW; ++r) acc[r] = 0.0f;

    __syncthreads();

    // acc[r] += max(Q_r[c], g_r[lane]) * (lane < c)
    #pragma unroll
    for (int c = 1; c < NBEST; ++c) {
        float4 qa = q4[wib][0][c];
        float4 qb = q4[wib][1][c];
        float mm = (lane < c) ? 1.0f : 0.0f;           // shared by 8 rows
        acc[0] = fmaf(fmaxf(qa.x, gv[0]), mm, acc[0]);
        acc[1] = fmaf(fmaxf(qa.y, gv[1]), mm, acc[1]);
        acc[2] = fmaf(fmaxf(qa.z, gv[2]), mm, acc[2]);
        acc[3] = fmaf(fmaxf(qa.w, gv[3]), mm, acc[3]);
        acc[4] = fmaf(fmaxf(qb.x, gv[4]), mm, acc[4]);
        acc[5] = fmaf(fmaxf(qb.y, gv[5]), mm, acc[5]);
        acc[6] = fmaf(fmaxf(qb.z, gv[6]), mm, acc[6]);
        acc[7] = fmaf(fmaxf(qb.w, gv[7]), mm, acc[7]);
    }

    // Subtract g_i * count, tail-guard, mean denominator.
    const float cntf = (float)((NBEST - 1) - lane);
    float accs = 0.0f;
    #pragma unroll
    for (int r = 0; r < RPW; ++r) {
        float ar = fmaf(-gv[r], cntf, acc[r]);
        accs += (b0 + r < B) ? ar : 0.0f;
    }
    int cnt = (NBEST - 1) - lane;                      // lane 63: acc==0
    float accv = accs / (float)(cnt > 0 ? cnt : 1);

    // Wave-64 shuffle reduction, then block combine.
    #pragma unroll
    for (int off = 32; off > 0; off >>= 1)
        accv += __shfl_down(accv, off);

    __shared__ float wsum[4];
    if (lane == 0) wsum[wib] = accv;
    __syncthreads();
    if (threadIdx.x == 0)
        ws[blockIdx.x] = wsum[0] + wsum[1] + wsum[2] + wsum[3];
}

// Single-block reduction of per-block partials.
__global__ __launch_bounds__(256)
void sml_reduce(const float* __restrict__ ws, float* __restrict__ out, int n)
{
    const int lane = threadIdx.x & 63;
    const int wid  = threadIdx.x >> 6;
    float s = 0.0f;
    for (int i = threadIdx.x; i < n; i += 256) s += ws[i];
    #pragma unroll
    for (int off = 32; off > 0; off >>= 1)
        s += __shfl_down(s, off);
    __shared__ float wsum[4];
    if (lane == 0) wsum[wid] = s;
    __syncthreads();
    if (threadIdx.x == 0)
        out[0] = wsum[0] + wsum[1] + wsum[2] + wsum[3];
}

extern "C" void kernel_launch(void* const* d_in, const int* in_sizes, int n_in,
                              void* d_out, int out_size, void* d_ws, size_t ws_size,
                              hipStream_t stream)
{
    const float* scores    = (const float*)d_in[0];
    const unsigned int* wr = (const unsigned int*)d_in[1];
    const int B = in_sizes[0] / NBEST;

    const int rows_per_block = 4 * RPW;                           // 32
    const int blocks = (B + rows_per_block - 1) / rows_per_block; // 512
    sml_kernel<<<blocks, 256, 0, stream>>>(scores, wr, (float*)d_ws, B);
    sml_reduce<<<1, 256, 0, stream>>>((const float*)d_ws, (float*)d_out, blocks);
}

// Round 10
// 14.935 us; speedup vs baseline: 1.4464x; 1.0209x over previous
//
#include <hip/hip_runtime.h>

#define MARGIN 0.1f
#define NBEST 64
#define RPW 4          // rows per wave (4 -> 4096 waves -> 4/SIMD occupancy)

// One wave processes 4 rows; 1024 blocks keep 4 waves/SIMD resident to hide
// the cold-cache gather latency (replays start L2/L3-cold from the harness's
// ws poison fill). LDS holds Q = g + margin as one float4 per column; each
// column is a single broadcast ds_read_b128 (same addr on all lanes ->
// conflict-free; LDS pipe overlaps VALU). Pair cost = v_max + v_fma via
// max(x-b,0) = max(x,b) - b; the -g_i*count term folds into one epilogue
// fma per row. Plain-store partials; 1-block kernel reduces. No atomics.
__global__ __launch_bounds__(256)
void sml_kernel(const float* __restrict__ scores,
                const unsigned int* __restrict__ wr32,
                float* __restrict__ ws, int B)
{
    const int lane = threadIdx.x & 63;
    const int wib  = threadIdx.x >> 6;                 // wave-in-block 0..3
    const int b0   = (blockIdx.x * 4 + wib) * RPW;     // first row of wave

    // werRank width probe (int64 vs int32), wave-uniform: int64 values in
    // [0,64) -> every odd int32 word is 0.
    unsigned int probe = wr32[2 * lane + 1];
    const bool is64 = (__all(probe == 0u) != 0);

    // Gather: lane owns column i=lane of each of its 4 rows. Independent
    // rank loads issued back-to-back, then the 4 dependent score gathers.
    unsigned int rk[RPW];
    #pragma unroll
    for (int r = 0; r < RPW; ++r) {
        int bc = min(b0 + r, B - 1);
        rk[r] = is64 ? wr32[2 * (bc * NBEST + lane)] : wr32[bc * NBEST + lane];
    }
    float gv[RPW];
    #pragma unroll
    for (int r = 0; r < RPW; ++r) {
        int bc = min(b0 + r, B - 1);
        gv[r] = scores[bc * NBEST + (int)(rk[r] & (NBEST - 1))];
    }

    __shared__ float4 q4[4][NBEST];      // [wave][column], Q = g + margin
    q4[wib][lane] = make_float4(gv[0] + MARGIN, gv[1] + MARGIN,
                                gv[2] + MARGIN, gv[3] + MARGIN);

    float a0 = 0.0f, a1 = 0.0f, a2 = 0.0f, a3 = 0.0f;

    __syncthreads();

    // acc[r] += max(Q_r[c], g_r[lane]) * (lane < c)
    #pragma unroll
    for (int c = 1; c < NBEST; ++c) {
        float4 qa = q4[wib][c];
        float mm = (lane < c) ? 1.0f : 0.0f;           // shared by 4 rows
        a0 = fmaf(fmaxf(qa.x, gv[0]), mm, a0);
        a1 = fmaf(fmaxf(qa.y, gv[1]), mm, a1);
        a2 = fmaf(fmaxf(qa.z, gv[2]), mm, a2);
        a3 = fmaf(fmaxf(qa.w, gv[3]), mm, a3);
    }

    // Subtract g_i * count, tail-guard, mean denominator.
    const float cntf = (float)((NBEST - 1) - lane);
    float accs = 0.0f;
    accs += (b0 + 0 < B) ? fmaf(-gv[0], cntf, a0) : 0.0f;
    accs += (b0 + 1 < B) ? fmaf(-gv[1], cntf, a1) : 0.0f;
    accs += (b0 + 2 < B) ? fmaf(-gv[2], cntf, a2) : 0.0f;
    accs += (b0 + 3 < B) ? fmaf(-gv[3], cntf, a3) : 0.0f;
    int cnt = (NBEST - 1) - lane;                      // lane 63: acc==0
    float accv = accs / (float)(cnt > 0 ? cnt : 1);

    // Wave-64 shuffle reduction, then block combine.
    #pragma unroll
    for (int off = 32; off > 0; off >>= 1)
        accv += __shfl_down(accv, off);

    __shared__ float wsum[4];
    if (lane == 0) wsum[wib] = accv;
    __syncthreads();
    if (threadIdx.x == 0)
        ws[blockIdx.x] = wsum[0] + wsum[1] + wsum[2] + wsum[3];
}

// Single-block reduction of per-block partials.
__global__ __launch_bounds__(256)
void sml_reduce(const float* __restrict__ ws, float* __restrict__ out, int n)
{
    const int lane = threadIdx.x & 63;
    const int wid  = threadIdx.x >> 6;
    float s = 0.0f;
    for (int i = threadIdx.x; i < n; i += 256) s += ws[i];
    #pragma unroll
    for (int off = 32; off > 0; off >>= 1)
        s += __shfl_down(s, off);
    __shared__ float wsum[4];
    if (lane == 0) wsum[wid] = s;
    __syncthreads();
    if (threadIdx.x == 0)
        out[0] = wsum[0] + wsum[1] + wsum[2] + wsum[3];
}

extern "C" void kernel_launch(void* const* d_in, const int* in_sizes, int n_in,
                              void* d_out, int out_size, void* d_ws, size_t ws_size,
                              hipStream_t stream)
{
    const float* scores    = (const float*)d_in[0];
    const unsigned int* wr = (const unsigned int*)d_in[1];
    const int B = in_sizes[0] / NBEST;

    const int rows_per_block = 4 * RPW;                           // 16
    const int blocks = (B + rows_per_block - 1) / rows_per_block; // 1024
    sml_kernel<<<blocks, 256, 0, stream>>>(scores, wr, (float*)d_ws, B);
    sml_reduce<<<1, 256, 0, stream>>>((const float*)d_ws, (float*)d_out, blocks);
}